// Round 6
// baseline (86.324 us; speedup 1.0000x reference)
//
#include <hip/hip_runtime.h>
#include <math.h>

#define ALPHA 5e-4f
#define BIG 1e30f

typedef __attribute__((ext_vector_type(8))) short bf16x8;
typedef __attribute__((ext_vector_type(4))) float f32x4;

__device__ __forceinline__ unsigned short f2bf(float x) {
    unsigned u = __builtin_bit_cast(unsigned, x);
    unsigned r = (u + 0x7FFFu + ((u >> 16) & 1u)) >> 16;
    return (unsigned short)r;
}
__device__ __forceinline__ float bf2f(unsigned short b) {
    unsigned u = ((unsigned)b) << 16;
    return __builtin_bit_cast(float, u);
}

__device__ __forceinline__ void gload16(const short* g, short* l) {
    __builtin_amdgcn_global_load_lds(
        (const __attribute__((address_space(1))) void*)g,
        (__attribute__((address_space(3))) void*)l, 16, 0, 0);
}

// ---------------- Kernel A: f32 -> bf16 convert + row squared norms ----------------
__global__ __launch_bounds__(256)
void conv_rownorm_kernel(const float* __restrict__ X, short* __restrict__ Xb,
                         float* __restrict__ sqn, int d) {
    const int w = threadIdx.x >> 6, lane = threadIdx.x & 63;
    const int row = blockIdx.x * 4 + w;
    const float4* src = reinterpret_cast<const float4*>(X + (size_t)row * d);
    short4* dst = reinterpret_cast<short4*>(Xb + (size_t)row * d);
    float s = 0.f;
    const int nv = d >> 2;
    for (int c = lane; c < nv; c += 64) {
        float4 v = src[c];
        unsigned short b0 = f2bf(v.x), b1 = f2bf(v.y), b2 = f2bf(v.z), b3 = f2bf(v.w);
        float x0 = bf2f(b0), x1 = bf2f(b1), x2 = bf2f(b2), x3 = bf2f(b3);
        s += x0 * x0 + x1 * x1 + x2 * x2 + x3 * x3;
        dst[c] = make_short4((short)b0, (short)b1, (short)b2, (short)b3);
    }
    for (int off = 1; off < 64; off <<= 1) s += __shfl_xor(s, off, 64);
    if (lane == 0) sqn[row] = s;
}

// ---------------- Kernel B: bf16 MFMA gram, upper triangle, fused top-2 ----------------
// 128x128 tile, BK=32, 4 waves (2x2), 3-stage LDS ring + counted vmcnt.
// T2 both-sides LDS swizzle (slot (row,c) holds global chunk c^((row>>1)&3)).
// NEW (R6): supertile-major block ordering.  The 32x32 block triangle is split
// into 8x8-block supertiles (4 diag x36 + 6 off-diag x64 = 528).  Blocks are
// enumerated supertile-major, then chunked per XCD (bid&7): each XCD's 66
// concurrent blocks touch ~1 supertile's panels (~4-6 MB) -> XCD-L2-local.
#define BM 128
#define BN 128
#define BK 32

__global__ __launch_bounds__(256)
void gram_top2_mfma(const short* __restrict__ Xb, const float* __restrict__ sqn,
                    float* __restrict__ cand_s, int* __restrict__ cand_i,
                    int n, int d, int nb, int cpx) {
    __shared__ short As[3][BM * BK];
    __shared__ short Bs[3][BN * BK];

    // XCD chunking (round-robin HW dispatch assumed: xcd = bid & 7)
    const int bid = blockIdx.x;
    int rem = (bid & 7) * cpx + (bid >> 3);

    // supertile-major decode: supertiles (sr,sc) sr-major, 8x8 blocks each
    int sr = 0, sc = 0;
    {
        bool done = false;
        for (sr = 0; sr < 4 && !done; ++sr) {
            for (sc = sr; sc < 4; ++sc) {
                int cnt = (sr == sc) ? 36 : 64;
                if (rem < cnt) { done = true; break; }
                rem -= cnt;
            }
        }
        --sr;                               // undo loop increment on exit
    }
    int rb, cb;
    if (sr == sc) {                         // diagonal supertile: triangular local
        int r = 0;
        while (rem >= 8 - r) { rem -= 8 - r; ++r; }
        rb = sr * 8 + r; cb = sc * 8 + r + rem;
    } else {
        rb = sr * 8 + (rem >> 3); cb = sc * 8 + (rem & 7);
    }

    const int row0 = rb * BM, col0 = cb * BN;
    const int t = threadIdx.x;
    const int w = t >> 6, l = t & 63;
    const int wr = w >> 1, wc = w & 1;
    const int lc = l & 15, lg = l >> 4;

    f32x4 acc[4][4];
#pragma unroll
    for (int i = 0; i < 4; ++i)
#pragma unroll
        for (int j = 0; j < 4; ++j) acc[i][j] = (f32x4){0.f, 0.f, 0.f, 0.f};

    const int gchunk = (t & 3) ^ ((t >> 3) & 3);
    const size_t gA0 = (size_t)(row0 + (t >> 2)) * d + gchunk * 8;
    const size_t gB0 = (size_t)(col0 + (t >> 2)) * d + gchunk * 8;
    const size_t rstep = (size_t)64 * d;
    const int kswz = (lg ^ ((lc >> 1) & 3)) * 8;
    const int wbase = w * 512;

    const int nsteps = d / BK;             // 32

    // prologue: stage 0 -> ring0, stage 1 -> ring1
    {
        short* la = As[0] + wbase;  short* lb = Bs[0] + wbase;
        gload16(Xb + gA0, la);          gload16(Xb + gA0 + rstep, la + 2048);
        gload16(Xb + gB0, lb);          gload16(Xb + gB0 + rstep, lb + 2048);
        la = As[1] + wbase;  lb = Bs[1] + wbase;
        gload16(Xb + gA0 + BK, la);     gload16(Xb + gA0 + BK + rstep, la + 2048);
        gload16(Xb + gB0 + BK, lb);     gload16(Xb + gB0 + BK + rstep, lb + 2048);
    }

    int s0 = 0, s1 = 1, s2 = 2;            // ring indices: read s0, issue into s2
    for (int ks = 0; ks < nsteps; ++ks) {
        if (ks + 2 < nsteps) {
            short* la = As[s2] + wbase;  short* lb = Bs[s2] + wbase;
            const size_t ko = (size_t)(ks + 2) * BK;
            gload16(Xb + gA0 + ko, la);      gload16(Xb + gA0 + ko + rstep, la + 2048);
            gload16(Xb + gB0 + ko, lb);      gload16(Xb + gB0 + ko + rstep, lb + 2048);
            asm volatile("s_waitcnt vmcnt(8)" ::: "memory");
        } else if (ks + 1 < nsteps) {
            asm volatile("s_waitcnt vmcnt(4)" ::: "memory");
        } else {
            asm volatile("s_waitcnt vmcnt(0)" ::: "memory");
        }
        __builtin_amdgcn_s_barrier();      // stage ks visible to all waves

        bf16x8 a[4], b[4];
#pragma unroll
        for (int mi = 0; mi < 4; ++mi)
            a[mi] = *reinterpret_cast<const bf16x8*>(&As[s0][(wr * 64 + mi * 16 + lc) * BK + kswz]);
#pragma unroll
        for (int ni = 0; ni < 4; ++ni)
            b[ni] = *reinterpret_cast<const bf16x8*>(&Bs[s0][(wc * 64 + ni * 16 + lc) * BK + kswz]);
#pragma unroll
        for (int mi = 0; mi < 4; ++mi)
#pragma unroll
            for (int ni = 0; ni < 4; ++ni)
                acc[mi][ni] = __builtin_amdgcn_mfma_f32_16x16x32_bf16(
                    a[mi], b[ni], acc[mi][ni], 0, 0, 0);

        asm volatile("s_waitcnt lgkmcnt(0)" ::: "memory");
        __builtin_amdgcn_s_barrier();      // all reads of s0 done -> s0 reusable
        int tmp = s0; s0 = s1; s1 = s2; s2 = tmp;
    }

    // ---- row-path epilogue: per-row top-2 over this wave's 64-col strip ----
    // C frag layout: col = lane&15, row = (lane>>4)*4 + reg.
    float sq_c[4];
#pragma unroll
    for (int ni = 0; ni < 4; ++ni) sq_c[ni] = sqn[col0 + wc * 64 + ni * 16 + lc];
    const int strip_r = cb * 2 + wc;

#pragma unroll
    for (int mi = 0; mi < 4; ++mi) {
#pragma unroll
        for (int j = 0; j < 4; ++j) {
            const int grow = row0 + wr * 64 + mi * 16 + lg * 4 + j;
            float s1v = BIG, s2v = BIG;
            int i1 = -1, i2 = -1;
#pragma unroll
            for (int ni = 0; ni < 4; ++ni) {
                const int gcol = col0 + wc * 64 + ni * 16 + lc;
                float s = sq_c[ni] - 2.f * acc[mi][ni][j];
                if (gcol == grow) s = BIG;   // exclude self (diag blocks)
                if (s < s1v) { s2v = s1v; i2 = i1; s1v = s; i1 = gcol; }
                else if (s < s2v) { s2v = s; i2 = gcol; }
            }
            for (int off = 1; off < 16; off <<= 1) {
                float b1 = __shfl_xor(s1v, off, 16);
                int  bi1 = __shfl_xor(i1, off, 16);
                float b2 = __shfl_xor(s2v, off, 16);
                int  bi2 = __shfl_xor(i2, off, 16);
                if (b1 < s1v) { s2v = s1v; i2 = i1; s1v = b1; i1 = bi1; }
                else if (b1 < s2v) { s2v = b1; i2 = bi1; }
                if (b2 < s2v) { s2v = b2; i2 = bi2; }
            }
            if (lc == 0) {
                size_t base = ((size_t)grow * 64 + strip_r) * 2;
                cand_s[base] = s1v; cand_s[base + 1] = s2v;
                cand_i[base] = i1; cand_i[base + 1] = i2;
            }
        }
    }

    // ---- col-path epilogue (off-diagonal blocks): per-col top-2 over 64 rows ----
    if (rb != cb) {
        float sq_r[4][4];
#pragma unroll
        for (int mi = 0; mi < 4; ++mi)
#pragma unroll
            for (int j = 0; j < 4; ++j)
                sq_r[mi][j] = sqn[row0 + wr * 64 + mi * 16 + lg * 4 + j];
        const int strip_c = rb * 2 + wr;

#pragma unroll
        for (int ni = 0; ni < 4; ++ni) {
            const int gcol = col0 + wc * 64 + ni * 16 + lc;
            float s1v = BIG, s2v = BIG;
            int i1 = -1, i2 = -1;
#pragma unroll
            for (int mi = 0; mi < 4; ++mi)
#pragma unroll
                for (int j = 0; j < 4; ++j) {
                    const int grow = row0 + wr * 64 + mi * 16 + lg * 4 + j;
                    float s = sq_r[mi][j] - 2.f * acc[mi][ni][j];
                    if (s < s1v) { s2v = s1v; i2 = i1; s1v = s; i1 = grow; }
                    else if (s < s2v) { s2v = s; i2 = grow; }
                }
#pragma unroll
            for (int off = 16; off < 64; off <<= 1) {
                float b1 = __shfl_xor(s1v, off, 64);
                int  bi1 = __shfl_xor(i1, off, 64);
                float b2 = __shfl_xor(s2v, off, 64);
                int  bi2 = __shfl_xor(i2, off, 64);
                if (b1 < s1v) { s2v = s1v; i2 = i1; s1v = b1; i1 = bi1; }
                else if (b1 < s2v) { s2v = b1; i2 = bi1; }
                if (b2 < s2v) { s2v = b2; i2 = bi2; }
            }
            if (lg == 0) {
                size_t base = ((size_t)gcol * 64 + strip_c) * 2;
                cand_s[base] = s1v; cand_s[base + 1] = s2v;
                cand_i[base] = i1; cand_i[base + 1] = i2;
            }
        }
    }
}

// ---------------- Kernel C: merge 128 candidates/row + edge terms ----------------
__global__ __launch_bounds__(256)
void merge_edges_kernel(const float* __restrict__ sqn,
                        const float* __restrict__ cand_s, const int* __restrict__ cand_i,
                        const int* __restrict__ yb, const float* __restrict__ yo,
                        float* __restrict__ partial, int ncls) {
    const int w = threadIdx.x >> 6, lane = threadIdx.x & 63;
    const int row = blockIdx.x * 4 + w;

    float2 cs = reinterpret_cast<const float2*>(cand_s + (size_t)row * 128)[lane];
    int2   ci = reinterpret_cast<const int2*>(cand_i + (size_t)row * 128)[lane];
    float s1 = cs.x, s2 = cs.y;
    int i1 = ci.x, i2 = ci.y;
    if (s2 < s1) { float ts = s1; s1 = s2; s2 = ts; int ti = i1; i1 = i2; i2 = ti; }

    for (int off = 1; off < 64; off <<= 1) {
        float b1 = __shfl_xor(s1, off, 64);
        int  bi1 = __shfl_xor(i1, off, 64);
        float b2 = __shfl_xor(s2, off, 64);
        int  bi2 = __shfl_xor(i2, off, 64);
        if (b1 < s1) { s2 = s1; i2 = i1; s1 = b1; i1 = bi1; }
        else if (b1 < s2) { s2 = b1; i2 = bi1; }
        if (b2 < s2) { s2 = b2; i2 = bi2; }
    }
    const int yr = yb[row];
    const float sr = sqn[row];
    float w1 = ((yr == yb[i1]) ? 1.f : -1.f) * expf(-sqrtf(fmaxf(sr + s1, 0.f)));
    float w2 = ((yr == yb[i2]) ? 1.f : -1.f) * expf(-sqrtf(fmaxf(sr + s2, 0.f)));

    const float4* yr4 = reinterpret_cast<const float4*>(yo + (size_t)row * ncls);
    const float4* y14 = reinterpret_cast<const float4*>(yo + (size_t)i1 * ncls);
    const float4* y24 = reinterpret_cast<const float4*>(yo + (size_t)i2 * ncls);
    const int nv4 = ncls >> 2;             // 250
    float a1 = 0.f, a2 = 0.f;
    for (int c = lane; c < nv4; c += 64) {
        float4 v = yr4[c];
        float4 u1 = y14[c];
        float4 u2 = y24[c];
        float tx = v.x - u1.x, ty = v.y - u1.y, tz = v.z - u1.z, tw = v.w - u1.w;
        a1 = fmaf(tx, tx, fmaf(ty, ty, fmaf(tz, tz, fmaf(tw, tw, a1))));
        tx = v.x - u2.x; ty = v.y - u2.y; tz = v.z - u2.z; tw = v.w - u2.w;
        a2 = fmaf(tx, tx, fmaf(ty, ty, fmaf(tz, tz, fmaf(tw, tw, a2))));
    }
    for (int c = (nv4 << 2) + lane; c < ncls; c += 64) {   // tail (empty for 1000)
        float v = yo[(size_t)row * ncls + c];
        float t1 = v - yo[(size_t)i1 * ncls + c];
        float t2 = v - yo[(size_t)i2 * ncls + c];
        a1 = fmaf(t1, t1, a1);
        a2 = fmaf(t2, t2, a2);
    }
    for (int off = 1; off < 64; off <<= 1) {
        a1 += __shfl_xor(a1, off, 64);
        a2 += __shfl_xor(a2, off, 64);
    }
    if (lane == 0)
        partial[row] = w1 * sqrtf(a1) + w2 * sqrtf(a2);
}

// ---------------- Kernel D: final reduction of n partials ----------------
__global__ __launch_bounds__(256)
void final_reduce_kernel(const float* __restrict__ partial, float* __restrict__ out, int n) {
    const int t = threadIdx.x;
    __shared__ float red[4];
    float s = 0.f;
    const int nv4 = n >> 2;
    const float4* p4 = reinterpret_cast<const float4*>(partial);
    for (int c = t; c < nv4; c += 256) {
        float4 v = p4[c];
        s += v.x + v.y + v.z + v.w;
    }
    for (int off = 1; off < 64; off <<= 1) s += __shfl_xor(s, off, 64);
    if ((t & 63) == 0) red[t >> 6] = s;
    __syncthreads();
    if (t == 0) out[0] = ALPHA * (red[0] + red[1] + red[2] + red[3]);
}

extern "C" void kernel_launch(void* const* d_in, const int* in_sizes, int n_in,
                              void* d_out, int out_size, void* d_ws, size_t ws_size,
                              hipStream_t stream) {
    const float* X  = (const float*)d_in[0];
    const int*   yb = (const int*)d_in[1];
    const float* yo = (const float*)d_in[2];
    float* out = (float*)d_out;

    const int n    = in_sizes[1];          // 4096
    const int d    = in_sizes[0] / n;      // 1024
    const int ncls = in_sizes[2] / n;      // 1000
    const int nb   = n / BM;               // 32 row/col blocks; 64 strips

    // workspace: sqn | Xb (bf16) | cand_s | cand_i | partial
    char* wsb = (char*)d_ws;
    size_t off = 0;
    float* sqn = (float*)(wsb + off);    off += ((size_t)n * 4 + 255) & ~(size_t)255;
    short* Xb  = (short*)(wsb + off);    off += ((size_t)n * d * 2 + 255) & ~(size_t)255;
    float* cand_s = (float*)(wsb + off); off += ((size_t)n * 64 * 2 * 4 + 255) & ~(size_t)255;
    int*   cand_i = (int*)(wsb + off);   off += ((size_t)n * 64 * 2 * 4 + 255) & ~(size_t)255;
    float* partial = (float*)(wsb + off);

    conv_rownorm_kernel<<<n / 4, 256, 0, stream>>>(X, Xb, sqn, d);

    const int ntri = nb * (nb + 1) / 2;    // 528 (divisible by 8)
    const int cpx  = ntri / 8;             // 66 blocks per XCD chunk
    gram_top2_mfma<<<ntri, 256, 0, stream>>>(Xb, sqn, cand_s, cand_i, n, d, nb, cpx);

    merge_edges_kernel<<<n / 4, 256, 0, stream>>>(sqn, cand_s, cand_i, yb, yo, partial, ncls);

    final_reduce_kernel<<<1, 256, 0, stream>>>(partial, out, n);
}

// Round 7
// 82.627 us; speedup vs baseline: 1.0447x; 1.0447x over previous
//
#include <hip/hip_runtime.h>
#include <math.h>

#define ALPHA 5e-4f
#define BIG 1e30f

typedef __attribute__((ext_vector_type(8))) short bf16x8;
typedef __attribute__((ext_vector_type(4))) float f32x4;

__device__ __forceinline__ unsigned short f2bf(float x) {
    unsigned u = __builtin_bit_cast(unsigned, x);
    unsigned r = (u + 0x7FFFu + ((u >> 16) & 1u)) >> 16;
    return (unsigned short)r;
}
__device__ __forceinline__ float bf2f(unsigned short b) {
    unsigned u = ((unsigned)b) << 16;
    return __builtin_bit_cast(float, u);
}

__device__ __forceinline__ void gload16(const short* g, short* l) {
    __builtin_amdgcn_global_load_lds(
        (const __attribute__((address_space(1))) void*)g,
        (__attribute__((address_space(3))) void*)l, 16, 0, 0);
}

// ---------------- Kernel A: f32 -> bf16 convert + row squared norms ----------------
__global__ __launch_bounds__(256)
void conv_rownorm_kernel(const float* __restrict__ X, short* __restrict__ Xb,
                         float* __restrict__ sqn, int d) {
    const int w = threadIdx.x >> 6, lane = threadIdx.x & 63;
    const int row = blockIdx.x * 4 + w;
    const float4* src = reinterpret_cast<const float4*>(X + (size_t)row * d);
    short4* dst = reinterpret_cast<short4*>(Xb + (size_t)row * d);
    float s = 0.f;
    const int nv = d >> 2;
    for (int c = lane; c < nv; c += 64) {
        float4 v = src[c];
        unsigned short b0 = f2bf(v.x), b1 = f2bf(v.y), b2 = f2bf(v.z), b3 = f2bf(v.w);
        float x0 = bf2f(b0), x1 = bf2f(b1), x2 = bf2f(b2), x3 = bf2f(b3);
        s += x0 * x0 + x1 * x1 + x2 * x2 + x3 * x3;
        dst[c] = make_short4((short)b0, (short)b1, (short)b2, (short)b3);
    }
    for (int off = 1; off < 64; off <<= 1) s += __shfl_xor(s, off, 64);
    if (lane == 0) sqn[row] = s;
}

// ---------------- Kernel B: bf16 MFMA gram, upper triangle, fused top-2 ----------------
// R7: 256x256 tile, 512 threads = 8 waves (2M x 4N), per-wave 128x64 output
// (acc 8x4 frags of 16x16).  BK=32, 3-stage LDS ring + counted vmcnt, T2
// both-sides swizzle (slot (row,c) holds global chunk c^((row>>1)&3)).
// Triangle of 16x16 blocks = 136 = 17*8 -> flat XCD chunking (cpx=17).
// Row path  -> col strips cb*4+wcn.   Col path (rb!=cb) -> per-64-row half
// strips rb*4 + wr*2 + half.  Union over blocks = exactly 64 strips/row.
#define BM 256
#define BN 256
#define BK 32

__global__ __launch_bounds__(512, 2)
void gram_top2_mfma(const short* __restrict__ Xb, const float* __restrict__ sqn,
                    float* __restrict__ cand_s, int* __restrict__ cand_i,
                    int n, int d, int nb, int cpx) {
    __shared__ short As[3][BM * BK];
    __shared__ short Bs[3][BN * BK];

    // flat XCD chunking (as in R5), then triangular decode over nb=16
    const int bid = blockIdx.x;
    int rem = (bid & 7) * cpx + (bid >> 3);
    int rb = 0;
    while (rem >= nb - rb) { rem -= nb - rb; ++rb; }
    const int cb = rb + rem;

    const int row0 = rb * BM, col0 = cb * BN;
    const int t = threadIdx.x;
    const int w = t >> 6, l = t & 63;
    const int wr = w >> 2, wcn = w & 3;        // 2M x 4N wave grid
    const int lc = l & 15, lg = l >> 4;

    f32x4 acc[8][4];
#pragma unroll
    for (int i = 0; i < 8; ++i)
#pragma unroll
        for (int j = 0; j < 4; ++j) acc[i][j] = (f32x4){0.f, 0.f, 0.f, 0.f};

    // staging: thread t covers rows t>>2 and (t>>2)+128, chunk slot t&3.
    // source chunk = slot ^ ((row>>1)&3); (row>>1)&3 == (t>>3)&3, invariant +128.
    const int gchunk = (t & 3) ^ ((t >> 3) & 3);
    const size_t gA0 = (size_t)(row0 + (t >> 2)) * d + gchunk * 8;
    const size_t gB0 = (size_t)(col0 + (t >> 2)) * d + gchunk * 8;
    const size_t rstep = (size_t)128 * d;      // +128 rows
    const int kswz = (lg ^ ((lc >> 1) & 3)) * 8;
    const int wbase = w * 512;                 // wave w stages rows [w*16, w*16+16)

    const int nsteps = d / BK;                 // 32

    // prologue: stages 0,1
#pragma unroll
    for (int s = 0; s < 2; ++s) {
        short* la = As[s] + wbase;  short* lb = Bs[s] + wbase;
        const size_t ko = (size_t)s * BK;
        gload16(Xb + gA0 + ko, la);        gload16(Xb + gA0 + ko + rstep, la + 4096);
        gload16(Xb + gB0 + ko, lb);        gload16(Xb + gB0 + ko + rstep, lb + 4096);
    }

    int s0 = 0, s1 = 1, s2 = 2;                // ring: read s0, issue into s2
    for (int ks = 0; ks < nsteps; ++ks) {
        if (ks + 2 < nsteps) {
            short* la = As[s2] + wbase;  short* lb = Bs[s2] + wbase;
            const size_t ko = (size_t)(ks + 2) * BK;
            gload16(Xb + gA0 + ko, la);    gload16(Xb + gA0 + ko + rstep, la + 4096);
            gload16(Xb + gB0 + ko, lb);    gload16(Xb + gB0 + ko + rstep, lb + 4096);
            asm volatile("s_waitcnt vmcnt(8)" ::: "memory");
        } else if (ks + 1 < nsteps) {
            asm volatile("s_waitcnt vmcnt(4)" ::: "memory");
        } else {
            asm volatile("s_waitcnt vmcnt(0)" ::: "memory");
        }
        __builtin_amdgcn_s_barrier();          // stage ks visible to all waves

        bf16x8 a[8], b[4];
#pragma unroll
        for (int mi = 0; mi < 8; ++mi)
            a[mi] = *reinterpret_cast<const bf16x8*>(&As[s0][(wr * 128 + mi * 16 + lc) * BK + kswz]);
#pragma unroll
        for (int ni = 0; ni < 4; ++ni)
            b[ni] = *reinterpret_cast<const bf16x8*>(&Bs[s0][(wcn * 64 + ni * 16 + lc) * BK + kswz]);
#pragma unroll
        for (int mi = 0; mi < 8; ++mi)
#pragma unroll
            for (int ni = 0; ni < 4; ++ni)
                acc[mi][ni] = __builtin_amdgcn_mfma_f32_16x16x32_bf16(
                    a[mi], b[ni], acc[mi][ni], 0, 0, 0);

        asm volatile("s_waitcnt lgkmcnt(0)" ::: "memory");
        __builtin_amdgcn_s_barrier();          // reads of s0 done -> s0 reusable
        int tmp = s0; s0 = s1; s1 = s2; s2 = tmp;
    }

    // ---- row-path epilogue: per-row top-2 over this wave's 64-col strip ----
    // C frag layout: col = lane&15, row = (lane>>4)*4 + reg.
    float sq_c[4];
#pragma unroll
    for (int ni = 0; ni < 4; ++ni) sq_c[ni] = sqn[col0 + wcn * 64 + ni * 16 + lc];
    const int strip_r = cb * 4 + wcn;

#pragma unroll
    for (int mi = 0; mi < 8; ++mi) {
#pragma unroll
        for (int j = 0; j < 4; ++j) {
            const int grow = row0 + wr * 128 + mi * 16 + lg * 4 + j;
            float s1v = BIG, s2v = BIG;
            int i1 = -1, i2 = -1;
#pragma unroll
            for (int ni = 0; ni < 4; ++ni) {
                const int gcol = col0 + wcn * 64 + ni * 16 + lc;
                float s = sq_c[ni] - 2.f * acc[mi][ni][j];
                if (gcol == grow) s = BIG;     // exclude self (diag blocks)
                if (s < s1v) { s2v = s1v; i2 = i1; s1v = s; i1 = gcol; }
                else if (s < s2v) { s2v = s; i2 = gcol; }
            }
            for (int off = 1; off < 16; off <<= 1) {
                float b1 = __shfl_xor(s1v, off, 16);
                int  bi1 = __shfl_xor(i1, off, 16);
                float b2 = __shfl_xor(s2v, off, 16);
                int  bi2 = __shfl_xor(i2, off, 16);
                if (b1 < s1v) { s2v = s1v; i2 = i1; s1v = b1; i1 = bi1; }
                else if (b1 < s2v) { s2v = b1; i2 = bi1; }
                if (b2 < s2v) { s2v = b2; i2 = bi2; }
            }
            if (lc == 0) {
                size_t base = ((size_t)grow * 64 + strip_r) * 2;
                cand_s[base] = s1v; cand_s[base + 1] = s2v;
                cand_i[base] = i1; cand_i[base + 1] = i2;
            }
        }
    }

    // ---- col-path epilogue (off-diagonal blocks): per-col top-2 per 64-row half ----
    if (rb != cb) {
#pragma unroll
        for (int half = 0; half < 2; ++half) {
            const int strip_c = rb * 4 + wr * 2 + half;
#pragma unroll
            for (int ni = 0; ni < 4; ++ni) {
                const int gcol = col0 + wcn * 64 + ni * 16 + lc;
                float s1v = BIG, s2v = BIG;
                int i1 = -1, i2 = -1;
#pragma unroll
                for (int mq = 0; mq < 4; ++mq) {
                    const int mi = half * 4 + mq;
#pragma unroll
                    for (int j = 0; j < 4; ++j) {
                        const int grow = row0 + wr * 128 + mi * 16 + lg * 4 + j;
                        float s = sqn[grow] - 2.f * acc[mi][ni][j];
                        if (s < s1v) { s2v = s1v; i2 = i1; s1v = s; i1 = grow; }
                        else if (s < s2v) { s2v = s; i2 = grow; }
                    }
                }
#pragma unroll
                for (int off = 16; off < 64; off <<= 1) {
                    float b1 = __shfl_xor(s1v, off, 64);
                    int  bi1 = __shfl_xor(i1, off, 64);
                    float b2 = __shfl_xor(s2v, off, 64);
                    int  bi2 = __shfl_xor(i2, off, 64);
                    if (b1 < s1v) { s2v = s1v; i2 = i1; s1v = b1; i1 = bi1; }
                    else if (b1 < s2v) { s2v = b1; i2 = bi1; }
                    if (b2 < s2v) { s2v = b2; i2 = bi2; }
                }
                if (lg == 0) {
                    size_t base = ((size_t)gcol * 64 + strip_c) * 2;
                    cand_s[base] = s1v; cand_s[base + 1] = s2v;
                    cand_i[base] = i1; cand_i[base + 1] = i2;
                }
            }
        }
    }
}

// ---------------- Kernel C: merge 128 candidates/row + edge terms ----------------
__global__ __launch_bounds__(256)
void merge_edges_kernel(const float* __restrict__ sqn,
                        const float* __restrict__ cand_s, const int* __restrict__ cand_i,
                        const int* __restrict__ yb, const float* __restrict__ yo,
                        float* __restrict__ partial, int ncls) {
    const int w = threadIdx.x >> 6, lane = threadIdx.x & 63;
    const int row = blockIdx.x * 4 + w;

    float2 cs = reinterpret_cast<const float2*>(cand_s + (size_t)row * 128)[lane];
    int2   ci = reinterpret_cast<const int2*>(cand_i + (size_t)row * 128)[lane];
    float s1 = cs.x, s2 = cs.y;
    int i1 = ci.x, i2 = ci.y;
    if (s2 < s1) { float ts = s1; s1 = s2; s2 = ts; int ti = i1; i1 = i2; i2 = ti; }

    for (int off = 1; off < 64; off <<= 1) {
        float b1 = __shfl_xor(s1, off, 64);
        int  bi1 = __shfl_xor(i1, off, 64);
        float b2 = __shfl_xor(s2, off, 64);
        int  bi2 = __shfl_xor(i2, off, 64);
        if (b1 < s1) { s2 = s1; i2 = i1; s1 = b1; i1 = bi1; }
        else if (b1 < s2) { s2 = b1; i2 = bi1; }
        if (b2 < s2) { s2 = b2; i2 = bi2; }
    }
    const int yr = yb[row];
    const float sr = sqn[row];
    float w1 = ((yr == yb[i1]) ? 1.f : -1.f) * expf(-sqrtf(fmaxf(sr + s1, 0.f)));
    float w2 = ((yr == yb[i2]) ? 1.f : -1.f) * expf(-sqrtf(fmaxf(sr + s2, 0.f)));

    const float4* yr4 = reinterpret_cast<const float4*>(yo + (size_t)row * ncls);
    const float4* y14 = reinterpret_cast<const float4*>(yo + (size_t)i1 * ncls);
    const float4* y24 = reinterpret_cast<const float4*>(yo + (size_t)i2 * ncls);
    const int nv4 = ncls >> 2;             // 250
    float a1 = 0.f, a2 = 0.f;
    for (int c = lane; c < nv4; c += 64) {
        float4 v = yr4[c];
        float4 u1 = y14[c];
        float4 u2 = y24[c];
        float tx = v.x - u1.x, ty = v.y - u1.y, tz = v.z - u1.z, tw = v.w - u1.w;
        a1 = fmaf(tx, tx, fmaf(ty, ty, fmaf(tz, tz, fmaf(tw, tw, a1))));
        tx = v.x - u2.x; ty = v.y - u2.y; tz = v.z - u2.z; tw = v.w - u2.w;
        a2 = fmaf(tx, tx, fmaf(ty, ty, fmaf(tz, tz, fmaf(tw, tw, a2))));
    }
    for (int c = (nv4 << 2) + lane; c < ncls; c += 64) {   // tail (empty for 1000)
        float v = yo[(size_t)row * ncls + c];
        float t1 = v - yo[(size_t)i1 * ncls + c];
        float t2 = v - yo[(size_t)i2 * ncls + c];
        a1 = fmaf(t1, t1, a1);
        a2 = fmaf(t2, t2, a2);
    }
    for (int off = 1; off < 64; off <<= 1) {
        a1 += __shfl_xor(a1, off, 64);
        a2 += __shfl_xor(a2, off, 64);
    }
    if (lane == 0)
        partial[row] = w1 * sqrtf(a1) + w2 * sqrtf(a2);
}

// ---------------- Kernel D: final reduction of n partials ----------------
__global__ __launch_bounds__(256)
void final_reduce_kernel(const float* __restrict__ partial, float* __restrict__ out, int n) {
    const int t = threadIdx.x;
    __shared__ float red[4];
    float s = 0.f;
    const int nv4 = n >> 2;
    const float4* p4 = reinterpret_cast<const float4*>(partial);
    for (int c = t; c < nv4; c += 256) {
        float4 v = p4[c];
        s += v.x + v.y + v.z + v.w;
    }
    for (int off = 1; off < 64; off <<= 1) s += __shfl_xor(s, off, 64);
    if ((t & 63) == 0) red[t >> 6] = s;
    __syncthreads();
    if (t == 0) out[0] = ALPHA * (red[0] + red[1] + red[2] + red[3]);
}

extern "C" void kernel_launch(void* const* d_in, const int* in_sizes, int n_in,
                              void* d_out, int out_size, void* d_ws, size_t ws_size,
                              hipStream_t stream) {
    const float* X  = (const float*)d_in[0];
    const int*   yb = (const int*)d_in[1];
    const float* yo = (const float*)d_in[2];
    float* out = (float*)d_out;

    const int n    = in_sizes[1];          // 4096
    const int d    = in_sizes[0] / n;      // 1024
    const int ncls = in_sizes[2] / n;      // 1000
    const int nb   = n / BM;               // 16 row/col blocks of 256; 64 strips

    // workspace: sqn | Xb (bf16) | cand_s | cand_i | partial
    char* wsb = (char*)d_ws;
    size_t off = 0;
    float* sqn = (float*)(wsb + off);    off += ((size_t)n * 4 + 255) & ~(size_t)255;
    short* Xb  = (short*)(wsb + off);    off += ((size_t)n * d * 2 + 255) & ~(size_t)255;
    float* cand_s = (float*)(wsb + off); off += ((size_t)n * 64 * 2 * 4 + 255) & ~(size_t)255;
    int*   cand_i = (int*)(wsb + off);   off += ((size_t)n * 64 * 2 * 4 + 255) & ~(size_t)255;
    float* partial = (float*)(wsb + off);

    conv_rownorm_kernel<<<n / 4, 256, 0, stream>>>(X, Xb, sqn, d);

    const int ntri = nb * (nb + 1) / 2;    // 136 = 17*8
    const int cpx  = ntri / 8;             // 17
    gram_top2_mfma<<<ntri, 512, 0, stream>>>(Xb, sqn, cand_s, cand_i, n, d, nb, cpx);

    merge_edges_kernel<<<n / 4, 256, 0, stream>>>(sqn, cand_s, cand_i, yb, yo, partial, ncls);

    final_reduce_kernel<<<1, 256, 0, stream>>>(partial, out, n);
}

// Round 8
// 64.849 us; speedup vs baseline: 1.3312x; 1.2741x over previous
//
#include <hip/hip_runtime.h>
#include <math.h>

#define ALPHA 5e-4f
#define BIG 1e30f

typedef __attribute__((ext_vector_type(8))) short bf16x8;
typedef __attribute__((ext_vector_type(4))) float f32x4;

__device__ __forceinline__ unsigned short f2bf(float x) {
    unsigned u = __builtin_bit_cast(unsigned, x);
    unsigned r = (u + 0x7FFFu + ((u >> 16) & 1u)) >> 16;
    return (unsigned short)r;
}
__device__ __forceinline__ float bf2f(unsigned short b) {
    unsigned u = ((unsigned)b) << 16;
    return __builtin_bit_cast(float, u);
}

__device__ __forceinline__ void gload16(const short* g, short* l) {
    __builtin_amdgcn_global_load_lds(
        (const __attribute__((address_space(1))) void*)g,
        (__attribute__((address_space(3))) void*)l, 16, 0, 0);
}

// ---------------- Kernel A: f32 -> bf16 convert + row squared norms ----------------
__global__ __launch_bounds__(256)
void conv_rownorm_kernel(const float* __restrict__ X, short* __restrict__ Xb,
                         float* __restrict__ sqn, int d) {
    const int w = threadIdx.x >> 6, lane = threadIdx.x & 63;
    const int row = blockIdx.x * 4 + w;
    const float4* src = reinterpret_cast<const float4*>(X + (size_t)row * d);
    short4* dst = reinterpret_cast<short4*>(Xb + (size_t)row * d);
    float s = 0.f;
    const int nv = d >> 2;
    for (int c = lane; c < nv; c += 64) {
        float4 v = src[c];
        unsigned short b0 = f2bf(v.x), b1 = f2bf(v.y), b2 = f2bf(v.z), b3 = f2bf(v.w);
        float x0 = bf2f(b0), x1 = bf2f(b1), x2 = bf2f(b2), x3 = bf2f(b3);
        s += x0 * x0 + x1 * x1 + x2 * x2 + x3 * x3;
        dst[c] = make_short4((short)b0, (short)b1, (short)b2, (short)b3);
    }
    for (int off = 1; off < 64; off <<= 1) s += __shfl_xor(s, off, 64);
    if (lane == 0) sqn[row] = s;
}

// ---------------- Kernel B: bf16 MFMA gram, upper triangle, fused top-2 ----------------
// R8: 128x128 tile, 512 threads = 8 waves (2M x 4N), per-wave 64x32 (acc 4x2).
// Same 48KB 3-stage LDS ring + counted vmcnt + T2 both-sides swizzle as R5,
// but 2x the waves per block -> ~16 waves/CU at 528 blocks (latency hiding).
// Candidate slots per global row (B = row>>7):
//   col-path (row as column in off-diag block (rb,B), rb<B): slot rb*2+wr  in [0,2B)
//   row-path (block (B,cb), cb>=B): slot 2B+(cb-B)*4+wcn               in [2B,128-2B)
// valid slots per row = 128-2B (contiguous); merge masks the tail.
#define BM 128
#define BN 128
#define BK 32

__global__ __launch_bounds__(512, 4)
void gram_top2_mfma(const short* __restrict__ Xb, const float* __restrict__ sqn,
                    float* __restrict__ cand_s, int* __restrict__ cand_i,
                    int n, int d, int nb, int cpx) {
    __shared__ short As[3][BM * BK];
    __shared__ short Bs[3][BN * BK];

    // flat XCD chunking, then triangular decode
    const int bid = blockIdx.x;
    int rem = (bid & 7) * cpx + (bid >> 3);
    int rb = 0;
    while (rem >= nb - rb) { rem -= nb - rb; ++rb; }
    const int cb = rb + rem;

    const int row0 = rb * BM, col0 = cb * BN;
    const int t = threadIdx.x;
    const int w = t >> 6, l = t & 63;
    const int wr = w >> 2, wcn = w & 3;        // 2M x 4N wave grid
    const int lc = l & 15, lg = l >> 4;

    f32x4 acc[4][2];
#pragma unroll
    for (int i = 0; i < 4; ++i)
#pragma unroll
        for (int j = 0; j < 2; ++j) acc[i][j] = (f32x4){0.f, 0.f, 0.f, 0.f};

    // staging: thread t -> row t>>2 (0..127), chunk slot t&3.
    // source chunk = slot ^ ((row>>1)&3) = (t&3) ^ ((t>>3)&3).
    const int gchunk = (t & 3) ^ ((t >> 3) & 3);
    const size_t gA0 = (size_t)(row0 + (t >> 2)) * d + gchunk * 8;
    const size_t gB0 = (size_t)(col0 + (t >> 2)) * d + gchunk * 8;
    const int kswz = (lg ^ ((lc >> 1) & 3)) * 8;
    const int wbase = w * 512;                 // wave w stages rows [w*16, w*16+16)

    const int nsteps = d / BK;                 // 32

    // prologue: stages 0,1 (2 gload16 per thread per stage)
#pragma unroll
    for (int s = 0; s < 2; ++s) {
        gload16(Xb + gA0 + s * BK, As[s] + wbase);
        gload16(Xb + gB0 + s * BK, Bs[s] + wbase);
    }

    int s0 = 0, s1 = 1, s2 = 2;                // ring: read s0, issue into s2
    for (int ks = 0; ks < nsteps; ++ks) {
        if (ks + 2 < nsteps) {
            const size_t ko = (size_t)(ks + 2) * BK;
            gload16(Xb + gA0 + ko, As[s2] + wbase);
            gload16(Xb + gB0 + ko, Bs[s2] + wbase);
            asm volatile("s_waitcnt vmcnt(4)" ::: "memory");   // stage ks landed
        } else if (ks + 1 < nsteps) {
            asm volatile("s_waitcnt vmcnt(2)" ::: "memory");
        } else {
            asm volatile("s_waitcnt vmcnt(0)" ::: "memory");
        }
        __builtin_amdgcn_s_barrier();          // stage ks visible to all waves

        bf16x8 a[4], b[2];
#pragma unroll
        for (int mi = 0; mi < 4; ++mi)
            a[mi] = *reinterpret_cast<const bf16x8*>(&As[s0][(wr * 64 + mi * 16 + lc) * BK + kswz]);
#pragma unroll
        for (int ni = 0; ni < 2; ++ni)
            b[ni] = *reinterpret_cast<const bf16x8*>(&Bs[s0][(wcn * 32 + ni * 16 + lc) * BK + kswz]);

        __builtin_amdgcn_s_setprio(1);
#pragma unroll
        for (int mi = 0; mi < 4; ++mi)
#pragma unroll
            for (int ni = 0; ni < 2; ++ni)
                acc[mi][ni] = __builtin_amdgcn_mfma_f32_16x16x32_bf16(
                    a[mi], b[ni], acc[mi][ni], 0, 0, 0);
        __builtin_amdgcn_s_setprio(0);

        asm volatile("s_waitcnt lgkmcnt(0)" ::: "memory");
        __builtin_amdgcn_s_barrier();          // reads of s0 done -> s0 reusable
        int tmp = s0; s0 = s1; s1 = s2; s2 = tmp;
    }

    // ---- row-path epilogue: per-row top-2 over this wave's 32-col strip ----
    // C frag layout: col = lane&15, row = (lane>>4)*4 + reg.
    float sq_c[2];
#pragma unroll
    for (int ni = 0; ni < 2; ++ni) sq_c[ni] = sqn[col0 + wcn * 32 + ni * 16 + lc];
    const int slot_r = 2 * rb + (cb - rb) * 4 + wcn;

#pragma unroll
    for (int mi = 0; mi < 4; ++mi) {
#pragma unroll
        for (int j = 0; j < 4; ++j) {
            const int grow = row0 + wr * 64 + mi * 16 + lg * 4 + j;
            float s1v = BIG, s2v = BIG;
            int i1 = -1, i2 = -1;
#pragma unroll
            for (int ni = 0; ni < 2; ++ni) {
                const int gcol = col0 + wcn * 32 + ni * 16 + lc;
                float s = sq_c[ni] - 2.f * acc[mi][ni][j];
                if (gcol == grow) s = BIG;     // exclude self (diag blocks)
                if (s < s1v) { s2v = s1v; i2 = i1; s1v = s; i1 = gcol; }
                else if (s < s2v) { s2v = s; i2 = gcol; }
            }
            for (int off = 1; off < 16; off <<= 1) {
                float b1 = __shfl_xor(s1v, off, 16);
                int  bi1 = __shfl_xor(i1, off, 16);
                float b2 = __shfl_xor(s2v, off, 16);
                int  bi2 = __shfl_xor(i2, off, 16);
                if (b1 < s1v) { s2v = s1v; i2 = i1; s1v = b1; i1 = bi1; }
                else if (b1 < s2v) { s2v = b1; i2 = bi1; }
                if (b2 < s2v) { s2v = b2; i2 = bi2; }
            }
            if (lc == 0) {
                size_t base = ((size_t)grow * 128 + slot_r) * 2;
                cand_s[base] = s1v; cand_s[base + 1] = s2v;
                cand_i[base] = i1; cand_i[base + 1] = i2;
            }
        }
    }

    // ---- col-path epilogue (off-diagonal blocks): per-col top-2 over wave's 64 rows ----
    if (rb != cb) {
        float sq_r[4][4];
#pragma unroll
        for (int mi = 0; mi < 4; ++mi)
#pragma unroll
            for (int j = 0; j < 4; ++j)
                sq_r[mi][j] = sqn[row0 + wr * 64 + mi * 16 + lg * 4 + j];
        const int slot_c = rb * 2 + wr;

#pragma unroll
        for (int ni = 0; ni < 2; ++ni) {
            const int gcol = col0 + wcn * 32 + ni * 16 + lc;
            float s1v = BIG, s2v = BIG;
            int i1 = -1, i2 = -1;
#pragma unroll
            for (int mi = 0; mi < 4; ++mi)
#pragma unroll
                for (int j = 0; j < 4; ++j) {
                    const int grow = row0 + wr * 64 + mi * 16 + lg * 4 + j;
                    float s = sq_r[mi][j] - 2.f * acc[mi][ni][j];
                    if (s < s1v) { s2v = s1v; i2 = i1; s1v = s; i1 = grow; }
                    else if (s < s2v) { s2v = s; i2 = grow; }
                }
#pragma unroll
            for (int off = 16; off < 64; off <<= 1) {
                float b1 = __shfl_xor(s1v, off, 64);
                int  bi1 = __shfl_xor(i1, off, 64);
                float b2 = __shfl_xor(s2v, off, 64);
                int  bi2 = __shfl_xor(i2, off, 64);
                if (b1 < s1v) { s2v = s1v; i2 = i1; s1v = b1; i1 = bi1; }
                else if (b1 < s2v) { s2v = b1; i2 = bi1; }
                if (b2 < s2v) { s2v = b2; i2 = bi2; }
            }
            if (lg == 0) {
                size_t base = ((size_t)gcol * 128 + slot_c) * 2;
                cand_s[base] = s1v; cand_s[base + 1] = s2v;
                cand_i[base] = i1; cand_i[base + 1] = i2;
            }
        }
    }
}

// ---------------- Kernel C: merge 128 slots/row + edge terms ----------------
// One wave per row; each lane handles slots 2*lane, 2*lane+1 (float4/int4).
__global__ __launch_bounds__(256)
void merge_edges_kernel(const float* __restrict__ sqn,
                        const float* __restrict__ cand_s, const int* __restrict__ cand_i,
                        const int* __restrict__ yb, const float* __restrict__ yo,
                        float* __restrict__ partial, int ncls) {
    const int w = threadIdx.x >> 6, lane = threadIdx.x & 63;
    const int row = blockIdx.x * 4 + w;
    const int valid = 128 - 2 * (row >> 7);

    float4 cs = reinterpret_cast<const float4*>(cand_s + (size_t)row * 256)[lane];
    int4   ci = reinterpret_cast<const int4*>(cand_i + (size_t)row * 256)[lane];
    float s1a = cs.x, s2a = cs.y, s1b = cs.z, s2b = cs.w;
    int   i1a = ci.x, i2a = ci.y, i1b = ci.z, i2b = ci.w;
    if (2 * lane     >= valid) { s1a = BIG; s2a = BIG; i1a = -1; i2a = -1; }
    if (2 * lane + 1 >= valid) { s1b = BIG; s2b = BIG; i1b = -1; i2b = -1; }

    // local top-2 of the two sorted pairs
    float s1, s2; int i1, i2;
    if (s1b < s1a) {
        s1 = s1b; i1 = i1b;
        if (s1a < s2b) { s2 = s1a; i2 = i1a; } else { s2 = s2b; i2 = i2b; }
    } else {
        s1 = s1a; i1 = i1a;
        if (s1b < s2a) { s2 = s1b; i2 = i1b; } else { s2 = s2a; i2 = i2a; }
    }

    for (int off = 1; off < 64; off <<= 1) {
        float b1 = __shfl_xor(s1, off, 64);
        int  bi1 = __shfl_xor(i1, off, 64);
        float b2 = __shfl_xor(s2, off, 64);
        int  bi2 = __shfl_xor(i2, off, 64);
        if (b1 < s1) { s2 = s1; i2 = i1; s1 = b1; i1 = bi1; }
        else if (b1 < s2) { s2 = b1; i2 = bi1; }
        if (b2 < s2) { s2 = b2; i2 = bi2; }
    }
    const int yr = yb[row];
    const float sr = sqn[row];
    float w1 = ((yr == yb[i1]) ? 1.f : -1.f) * expf(-sqrtf(fmaxf(sr + s1, 0.f)));
    float w2 = ((yr == yb[i2]) ? 1.f : -1.f) * expf(-sqrtf(fmaxf(sr + s2, 0.f)));

    const float4* yr4 = reinterpret_cast<const float4*>(yo + (size_t)row * ncls);
    const float4* y14 = reinterpret_cast<const float4*>(yo + (size_t)i1 * ncls);
    const float4* y24 = reinterpret_cast<const float4*>(yo + (size_t)i2 * ncls);
    const int nv4 = ncls >> 2;             // 250
    float a1 = 0.f, a2 = 0.f;
    for (int c = lane; c < nv4; c += 64) {
        float4 v = yr4[c];
        float4 u1 = y14[c];
        float4 u2 = y24[c];
        float tx = v.x - u1.x, ty = v.y - u1.y, tz = v.z - u1.z, tw = v.w - u1.w;
        a1 = fmaf(tx, tx, fmaf(ty, ty, fmaf(tz, tz, fmaf(tw, tw, a1))));
        tx = v.x - u2.x; ty = v.y - u2.y; tz = v.z - u2.z; tw = v.w - u2.w;
        a2 = fmaf(tx, tx, fmaf(ty, ty, fmaf(tz, tz, fmaf(tw, tw, a2))));
    }
    for (int c = (nv4 << 2) + lane; c < ncls; c += 64) {   // tail (empty for 1000)
        float v = yo[(size_t)row * ncls + c];
        float t1 = v - yo[(size_t)i1 * ncls + c];
        float t2 = v - yo[(size_t)i2 * ncls + c];
        a1 = fmaf(t1, t1, a1);
        a2 = fmaf(t2, t2, a2);
    }
    for (int off = 1; off < 64; off <<= 1) {
        a1 += __shfl_xor(a1, off, 64);
        a2 += __shfl_xor(a2, off, 64);
    }
    if (lane == 0)
        partial[row] = w1 * sqrtf(a1) + w2 * sqrtf(a2);
}

// ---------------- Kernel D: final reduction of n partials ----------------
__global__ __launch_bounds__(256)
void final_reduce_kernel(const float* __restrict__ partial, float* __restrict__ out, int n) {
    const int t = threadIdx.x;
    __shared__ float red[4];
    float s = 0.f;
    const int nv4 = n >> 2;
    const float4* p4 = reinterpret_cast<const float4*>(partial);
    for (int c = t; c < nv4; c += 256) {
        float4 v = p4[c];
        s += v.x + v.y + v.z + v.w;
    }
    for (int off = 1; off < 64; off <<= 1) s += __shfl_xor(s, off, 64);
    if ((t & 63) == 0) red[t >> 6] = s;
    __syncthreads();
    if (t == 0) out[0] = ALPHA * (red[0] + red[1] + red[2] + red[3]);
}

extern "C" void kernel_launch(void* const* d_in, const int* in_sizes, int n_in,
                              void* d_out, int out_size, void* d_ws, size_t ws_size,
                              hipStream_t stream) {
    const float* X  = (const float*)d_in[0];
    const int*   yb = (const int*)d_in[1];
    const float* yo = (const float*)d_in[2];
    float* out = (float*)d_out;

    const int n    = in_sizes[1];          // 4096
    const int d    = in_sizes[0] / n;      // 1024
    const int ncls = in_sizes[2] / n;      // 1000
    const int nb   = n / BM;               // 32 row/col blocks of 128

    // workspace: sqn | Xb (bf16) | cand_s | cand_i | partial
    char* wsb = (char*)d_ws;
    size_t off = 0;
    float* sqn = (float*)(wsb + off);    off += ((size_t)n * 4 + 255) & ~(size_t)255;
    short* Xb  = (short*)(wsb + off);    off += ((size_t)n * d * 2 + 255) & ~(size_t)255;
    float* cand_s = (float*)(wsb + off); off += ((size_t)n * 128 * 2 * 4 + 255) & ~(size_t)255;
    int*   cand_i = (int*)(wsb + off);   off += ((size_t)n * 128 * 2 * 4 + 255) & ~(size_t)255;
    float* partial = (float*)(wsb + off);

    conv_rownorm_kernel<<<n / 4, 256, 0, stream>>>(X, Xb, sqn, d);

    const int ntri = nb * (nb + 1) / 2;    // 528 = 66*8
    const int cpx  = ntri / 8;             // 66
    gram_top2_mfma<<<ntri, 512, 0, stream>>>(Xb, sqn, cand_s, cand_i, n, d, nb, cpx);

    merge_edges_kernel<<<n / 4, 256, 0, stream>>>(sqn, cand_s, cand_i, yb, yo, partial, ncls);

    final_reduce_kernel<<<1, 256, 0, stream>>>(partial, out, n);
}

// Round 9
// 56.176 us; speedup vs baseline: 1.5367x; 1.1544x over previous
//
#include <hip/hip_runtime.h>
#include <math.h>

#define ALPHA 5e-4f
#define BIG 1e30f

typedef __attribute__((ext_vector_type(4))) float f32x4;

__device__ __forceinline__ void gload16(const void* g, void* l) {
    __builtin_amdgcn_global_load_lds(
        (const __attribute__((address_space(1))) void*)g,
        (__attribute__((address_space(3))) void*)l, 16, 0, 0);
}

// ---------------- Kernel A: f32 -> fp8(e4m3) convert + exact f32 row norms ----------------
// One wave per row.  sqn32 = ||x_row||^2 of the ORIGINAL f32 values (bias-free
// distance metric); Xq = OCP e4m3 quantization (selection operand).
__global__ __launch_bounds__(256)
void conv_fp8_kernel(const float* __restrict__ X, unsigned char* __restrict__ Xq,
                     float* __restrict__ sqn32, int d) {
    const int w = threadIdx.x >> 6, lane = threadIdx.x & 63;
    const int row = blockIdx.x * 4 + w;
    const float4* src = reinterpret_cast<const float4*>(X + (size_t)row * d);
    int4* dst = reinterpret_cast<int4*>(Xq + (size_t)row * d);
    float s = 0.f;
    const int ng = d >> 4;                 // 16 floats / group
    for (int g = lane; g < ng; g += 64) {
        int wds[4];
#pragma unroll
        for (int q = 0; q < 4; ++q) {
            float4 v = src[g * 4 + q];
            s += v.x * v.x + v.y * v.y + v.z * v.z + v.w * v.w;
            int t0 = __builtin_amdgcn_cvt_pk_fp8_f32(v.x, v.y, 0, false);
            wds[q] = __builtin_amdgcn_cvt_pk_fp8_f32(v.z, v.w, t0, true);
        }
        dst[g] = make_int4(wds[0], wds[1], wds[2], wds[3]);
    }
    for (int off = 1; off < 64; off <<= 1) s += __shfl_xor(s, off, 64);
    if (lane == 0) sqn32[row] = s;
}

// ---------------- Kernel B: fp8 MFMA gram, upper triangle, fused top-2 ----------------
// 128x128 tile, BK=64 (bytes=elems), 256 threads = 4 waves (2x2), 3-stage LDS
// ring + counted vmcnt.  LDS rows are 64B = 8 chunks of 8B; swizzle (both
// sides): LDS chunk c' holds global chunk c' ^ s(row), s(row) = ((row>>1)&3)<<1
// (even XOR keeps 16B gload pairs intact).  Staging source offset:
// ((t&3)^((t>>3)&3))<<4.  Reads at chunk (ki*4+lg) ^ (((lc>>1)&3)<<1).
// Selection value s = sqn32[col] - 2*<xq_i, xq_j>  (bias-free metric).
#define BM 128
#define BN 128
#define BKB 64

__global__ __launch_bounds__(256)
void gram_top2_mfma(const unsigned char* __restrict__ Xq, const float* __restrict__ sqn,
                    float* __restrict__ cand_s, int* __restrict__ cand_i,
                    int n, int d, int nb, int cpx) {
    __shared__ unsigned char As[3][BM * BKB];   // 3 x 8KB
    __shared__ unsigned char Bs[3][BN * BKB];   // 3 x 8KB

    // flat XCD chunking, then triangular decode
    const int bid = blockIdx.x;
    int rem = (bid & 7) * cpx + (bid >> 3);
    int rb = 0;
    while (rem >= nb - rb) { rem -= nb - rb; ++rb; }
    const int cb = rb + rem;

    const int row0 = rb * BM, col0 = cb * BN;
    const int t = threadIdx.x;
    const int w = t >> 6, l = t & 63;
    const int wr = w >> 1, wc = w & 1;
    const int lc = l & 15, lg = l >> 4;

    f32x4 acc[4][4];
#pragma unroll
    for (int i = 0; i < 4; ++i)
#pragma unroll
        for (int j = 0; j < 4; ++j) acc[i][j] = (f32x4){0.f, 0.f, 0.f, 0.f};

    // staging: thread t -> row t>>2 (0..63) and +64; 16B quarter (t&3), swizzled
    const int gsw = ((t & 3) ^ ((t >> 3) & 3)) << 4;
    const size_t gA0 = (size_t)(row0 + (t >> 2)) * d + gsw;
    const size_t gB0 = (size_t)(col0 + (t >> 2)) * d + gsw;
    const size_t rstep = (size_t)64 * d;
    const int wbase = w * 1024;            // wave w: rows [16w,16w+16) (+64 at +4096)
    // read-side swizzled chunk base (bytes): ((lc>>1)&3)<<1 XOR, times 8
    const int rsw = ((lc >> 1) & 3) << 1;

    const int nsteps = d / BKB;            // 16

    // prologue: stages 0,1 (4 gloads per thread per stage)
#pragma unroll
    for (int s = 0; s < 2; ++s) {
        const size_t ko = (size_t)s * BKB;
        gload16(Xq + gA0 + ko, As[s] + wbase);
        gload16(Xq + gA0 + ko + rstep, As[s] + wbase + 4096);
        gload16(Xq + gB0 + ko, Bs[s] + wbase);
        gload16(Xq + gB0 + ko + rstep, Bs[s] + wbase + 4096);
    }

    int s0 = 0, s1 = 1, s2 = 2;            // ring: read s0, issue into s2
    for (int ks = 0; ks < nsteps; ++ks) {
        if (ks + 2 < nsteps) {
            const size_t ko = (size_t)(ks + 2) * BKB;
            gload16(Xq + gA0 + ko, As[s2] + wbase);
            gload16(Xq + gA0 + ko + rstep, As[s2] + wbase + 4096);
            gload16(Xq + gB0 + ko, Bs[s2] + wbase);
            gload16(Xq + gB0 + ko + rstep, Bs[s2] + wbase + 4096);
            asm volatile("s_waitcnt vmcnt(8)" ::: "memory");   // stage ks landed
        } else if (ks + 1 < nsteps) {
            asm volatile("s_waitcnt vmcnt(4)" ::: "memory");
        } else {
            asm volatile("s_waitcnt vmcnt(0)" ::: "memory");
        }
        __builtin_amdgcn_s_barrier();      // stage ks visible to all waves

        long long a[2][4], b[2][4];
#pragma unroll
        for (int ki = 0; ki < 2; ++ki) {
            const int ch = ((ki * 4 + lg) ^ rsw) * 8;
#pragma unroll
            for (int mi = 0; mi < 4; ++mi) {
                a[ki][mi] = *reinterpret_cast<const long long*>(
                    &As[s0][(wr * 64 + mi * 16 + lc) * 64 + ch]);
                b[ki][mi] = *reinterpret_cast<const long long*>(
                    &Bs[s0][(wc * 64 + mi * 16 + lc) * 64 + ch]);
            }
        }
#pragma unroll
        for (int mi = 0; mi < 4; ++mi)
#pragma unroll
            for (int ni = 0; ni < 4; ++ni) {
                acc[mi][ni] = __builtin_amdgcn_mfma_f32_16x16x32_fp8_fp8(
                    a[0][mi], b[0][ni], acc[mi][ni], 0, 0, 0);
                acc[mi][ni] = __builtin_amdgcn_mfma_f32_16x16x32_fp8_fp8(
                    a[1][mi], b[1][ni], acc[mi][ni], 0, 0, 0);
            }

        asm volatile("s_waitcnt lgkmcnt(0)" ::: "memory");
        __builtin_amdgcn_s_barrier();      // reads of s0 done -> s0 reusable
        int tmp = s0; s0 = s1; s1 = s2; s2 = tmp;
    }

    // ---- row-path epilogue: per-row top-2 over this wave's 64-col strip ----
    // C frag layout: col = lane&15, row = (lane>>4)*4 + reg.
    float sq_c[4];
#pragma unroll
    for (int ni = 0; ni < 4; ++ni) sq_c[ni] = sqn[col0 + wc * 64 + ni * 16 + lc];
    const int strip_r = cb * 2 + wc;

#pragma unroll
    for (int mi = 0; mi < 4; ++mi) {
#pragma unroll
        for (int j = 0; j < 4; ++j) {
            const int grow = row0 + wr * 64 + mi * 16 + lg * 4 + j;
            float s1v = BIG, s2v = BIG;
            int i1 = -1, i2 = -1;
#pragma unroll
            for (int ni = 0; ni < 4; ++ni) {
                const int gcol = col0 + wc * 64 + ni * 16 + lc;
                float s = sq_c[ni] - 2.f * acc[mi][ni][j];
                if (gcol == grow) s = BIG;   // exclude self (diag blocks)
                if (s < s1v) { s2v = s1v; i2 = i1; s1v = s; i1 = gcol; }
                else if (s < s2v) { s2v = s; i2 = gcol; }
            }
            for (int off = 1; off < 16; off <<= 1) {
                float b1 = __shfl_xor(s1v, off, 16);
                int  bi1 = __shfl_xor(i1, off, 16);
                float b2 = __shfl_xor(s2v, off, 16);
                int  bi2 = __shfl_xor(i2, off, 16);
                if (b1 < s1v) { s2v = s1v; i2 = i1; s1v = b1; i1 = bi1; }
                else if (b1 < s2v) { s2v = b1; i2 = bi1; }
                if (b2 < s2v) { s2v = b2; i2 = bi2; }
            }
            if (lc == 0) {
                size_t base = ((size_t)grow * 64 + strip_r) * 2;
                cand_s[base] = s1v; cand_s[base + 1] = s2v;
                cand_i[base] = i1; cand_i[base + 1] = i2;
            }
        }
    }

    // ---- col-path epilogue (off-diagonal blocks): per-col top-2 over 64 rows ----
    if (rb != cb) {
        float sq_r[4][4];
#pragma unroll
        for (int mi = 0; mi < 4; ++mi)
#pragma unroll
            for (int j = 0; j < 4; ++j)
                sq_r[mi][j] = sqn[row0 + wr * 64 + mi * 16 + lg * 4 + j];
        const int strip_c = rb * 2 + wr;

#pragma unroll
        for (int ni = 0; ni < 4; ++ni) {
            const int gcol = col0 + wc * 64 + ni * 16 + lc;
            float s1v = BIG, s2v = BIG;
            int i1 = -1, i2 = -1;
#pragma unroll
            for (int mi = 0; mi < 4; ++mi)
#pragma unroll
                for (int j = 0; j < 4; ++j) {
                    const int grow = row0 + wr * 64 + mi * 16 + lg * 4 + j;
                    float s = sq_r[mi][j] - 2.f * acc[mi][ni][j];
                    if (s < s1v) { s2v = s1v; i2 = i1; s1v = s; i1 = grow; }
                    else if (s < s2v) { s2v = s; i2 = grow; }
                }
#pragma unroll
            for (int off = 16; off < 64; off <<= 1) {
                float b1 = __shfl_xor(s1v, off, 64);
                int  bi1 = __shfl_xor(i1, off, 64);
                float b2 = __shfl_xor(s2v, off, 64);
                int  bi2 = __shfl_xor(i2, off, 64);
                if (b1 < s1v) { s2v = s1v; i2 = i1; s1v = b1; i1 = bi1; }
                else if (b1 < s2v) { s2v = b1; i2 = bi1; }
                if (b2 < s2v) { s2v = b2; i2 = bi2; }
            }
            if (lg == 0) {
                size_t base = ((size_t)gcol * 64 + strip_c) * 2;
                cand_s[base] = s1v; cand_s[base + 1] = s2v;
                cand_i[base] = i1; cand_i[base + 1] = i2;
            }
        }
    }
}

// ---------------- Kernel C: merge 128 candidates/row + edge terms ----------------
__global__ __launch_bounds__(256)
void merge_edges_kernel(const float* __restrict__ sqn,
                        const float* __restrict__ cand_s, const int* __restrict__ cand_i,
                        const int* __restrict__ yb, const float* __restrict__ yo,
                        float* __restrict__ partial, int ncls) {
    const int w = threadIdx.x >> 6, lane = threadIdx.x & 63;
    const int row = blockIdx.x * 4 + w;

    float2 cs = reinterpret_cast<const float2*>(cand_s + (size_t)row * 128)[lane];
    int2   ci = reinterpret_cast<const int2*>(cand_i + (size_t)row * 128)[lane];
    float s1 = cs.x, s2 = cs.y;
    int i1 = ci.x, i2 = ci.y;
    if (s2 < s1) { float ts = s1; s1 = s2; s2 = ts; int ti = i1; i1 = i2; i2 = ti; }

    for (int off = 1; off < 64; off <<= 1) {
        float b1 = __shfl_xor(s1, off, 64);
        int  bi1 = __shfl_xor(i1, off, 64);
        float b2 = __shfl_xor(s2, off, 64);
        int  bi2 = __shfl_xor(i2, off, 64);
        if (b1 < s1) { s2 = s1; i2 = i1; s1 = b1; i1 = bi1; }
        else if (b1 < s2) { s2 = b1; i2 = bi1; }
        if (b2 < s2) { s2 = b2; i2 = bi2; }
    }
    const int yr = yb[row];
    const float sr = sqn[row];
    float w1 = ((yr == yb[i1]) ? 1.f : -1.f) * expf(-sqrtf(fmaxf(sr + s1, 0.f)));
    float w2 = ((yr == yb[i2]) ? 1.f : -1.f) * expf(-sqrtf(fmaxf(sr + s2, 0.f)));

    const float4* yr4 = reinterpret_cast<const float4*>(yo + (size_t)row * ncls);
    const float4* y14 = reinterpret_cast<const float4*>(yo + (size_t)i1 * ncls);
    const float4* y24 = reinterpret_cast<const float4*>(yo + (size_t)i2 * ncls);
    const int nv4 = ncls >> 2;             // 250
    float a1 = 0.f, a2 = 0.f;
    for (int c = lane; c < nv4; c += 64) {
        float4 v = yr4[c];
        float4 u1 = y14[c];
        float4 u2 = y24[c];
        float tx = v.x - u1.x, ty = v.y - u1.y, tz = v.z - u1.z, tw = v.w - u1.w;
        a1 = fmaf(tx, tx, fmaf(ty, ty, fmaf(tz, tz, fmaf(tw, tw, a1))));
        tx = v.x - u2.x; ty = v.y - u2.y; tz = v.z - u2.z; tw = v.w - u2.w;
        a2 = fmaf(tx, tx, fmaf(ty, ty, fmaf(tz, tz, fmaf(tw, tw, a2))));
    }
    for (int c = (nv4 << 2) + lane; c < ncls; c += 64) {   // tail (empty for 1000)
        float v = yo[(size_t)row * ncls + c];
        float t1 = v - yo[(size_t)i1 * ncls + c];
        float t2 = v - yo[(size_t)i2 * ncls + c];
        a1 = fmaf(t1, t1, a1);
        a2 = fmaf(t2, t2, a2);
    }
    for (int off = 1; off < 64; off <<= 1) {
        a1 += __shfl_xor(a1, off, 64);
        a2 += __shfl_xor(a2, off, 64);
    }
    if (lane == 0)
        partial[row] = w1 * sqrtf(a1) + w2 * sqrtf(a2);
}

// ---------------- Kernel D: final reduction of n partials ----------------
__global__ __launch_bounds__(256)
void final_reduce_kernel(const float* __restrict__ partial, float* __restrict__ out, int n) {
    const int t = threadIdx.x;
    __shared__ float red[4];
    float s = 0.f;
    const int nv4 = n >> 2;
    const float4* p4 = reinterpret_cast<const float4*>(partial);
    for (int c = t; c < nv4; c += 256) {
        float4 v = p4[c];
        s += v.x + v.y + v.z + v.w;
    }
    for (int off = 1; off < 64; off <<= 1) s += __shfl_xor(s, off, 64);
    if ((t & 63) == 0) red[t >> 6] = s;
    __syncthreads();
    if (t == 0) out[0] = ALPHA * (red[0] + red[1] + red[2] + red[3]);
}

extern "C" void kernel_launch(void* const* d_in, const int* in_sizes, int n_in,
                              void* d_out, int out_size, void* d_ws, size_t ws_size,
                              hipStream_t stream) {
    const float* X  = (const float*)d_in[0];
    const int*   yb = (const int*)d_in[1];
    const float* yo = (const float*)d_in[2];
    float* out = (float*)d_out;

    const int n    = in_sizes[1];          // 4096
    const int d    = in_sizes[0] / n;      // 1024
    const int ncls = in_sizes[2] / n;      // 1000
    const int nb   = n / BM;               // 32 row/col blocks of 128

    // workspace: sqn32 | Xq (fp8) | cand_s | cand_i | partial
    char* wsb = (char*)d_ws;
    size_t off = 0;
    float* sqn32 = (float*)(wsb + off);         off += ((size_t)n * 4 + 255) & ~(size_t)255;
    unsigned char* Xq = (unsigned char*)(wsb + off); off += ((size_t)n * d + 255) & ~(size_t)255;
    float* cand_s = (float*)(wsb + off);        off += ((size_t)n * 64 * 2 * 4 + 255) & ~(size_t)255;
    int*   cand_i = (int*)(wsb + off);          off += ((size_t)n * 64 * 2 * 4 + 255) & ~(size_t)255;
    float* partial = (float*)(wsb + off);

    conv_fp8_kernel<<<n / 4, 256, 0, stream>>>(X, Xq, sqn32, d);

    const int ntri = nb * (nb + 1) / 2;    // 528 = 66*8
    const int cpx  = ntri / 8;             // 66
    gram_top2_mfma<<<ntri, 256, 0, stream>>>(Xq, sqn32, cand_s, cand_i, n, d, nb, cpx);

    merge_edges_kernel<<<n / 4, 256, 0, stream>>>(sqn32, cand_s, cand_i, yb, yo, partial, ncls);

    final_reduce_kernel<<<1, 256, 0, stream>>>(partial, out, n);
}